// Round 6
// baseline (76.700 us; speedup 1.0000x reference)
//
#include <hip/hip_runtime.h>
#include <math.h>

typedef _Float16 f16;
typedef _Float16 f16x2 __attribute__((ext_vector_type(2)));
typedef _Float16 f16x4 __attribute__((ext_vector_type(4)));
typedef _Float16 f16x8 __attribute__((ext_vector_type(8)));
typedef float f32x4 __attribute__((ext_vector_type(4)));

#define NVOX 48
#define F_ 16

// K-order: 64 pair-slots s (= kq), each holding taps (tap_a, tap_b):
//  s<50  (W): fd=s/10, r=s%10, fh=r>>1, fw=(r&1)*2     -> pair (fw, fw+1), xs-stride 1
//  50..59(H): q=s-50, fd=q>>1, fh=(q&1)*2, fw=4        -> pair (fh, fh+1), xs-stride 9
//  60..62(D): g=s-60, fd=g*2, fh=4, fw=4               -> pair (fd, fd+1), xs-stride 72
//            (s=62 second tap invalid; s=63 both invalid -> zero filters)
// xs layout: elem = d*72 + h*9 + w (stride-9 row padding), 4ch f16 per elem.

// ---------------------------------------------------------------------------
// Kernel 1: effective filter bank in MFMA fragment layout.
// efb[kq(64)][n(256)][j(8)] f16; j = half*4 + c (half = tap_a/tap_b, c = chan),
// n = f*16 + map. Folds radial shells, degree-shared w, sqrt((m>0?2:1)/(2n+1)).
// ---------------------------------------------------------------------------
__global__ void build_filters(const float* __restrict__ w, f16* __restrict__ efb) {
    int e = blockIdx.x * 256 + threadIdx.x;  // 0..131071
    int j = e & 7;
    int n = (e >> 3) & 255;
    int s = e >> 11;             // kq slot 0..63
    int half = j >> 2, c = j & 3, f = n >> 4, map = n & 15;

    int tap = 0;
    bool valid = true;
    if (s < 50)      { int fd = s / 10, r = s % 10, fh = r >> 1, fw = (r & 1) * 2 + half;
                       tap = fd * 25 + fh * 5 + fw; }
    else if (s < 60) { int q = s - 50, fd = q >> 1, fh = (q & 1) * 2 + half;
                       tap = fd * 25 + fh * 5 + 4; }
    else if (s == 60){ tap = (0 + half) * 25 + 24; }
    else if (s == 61){ tap = (2 + half) * 25 + 24; }
    else if (s == 62){ tap = 4 * 25 + 24; valid = (half == 0); }
    else             { valid = false; }

    float outv = 0.f;
    if (valid) {
        int fd = tap / 25, fh = (tap / 5) % 5, fw = tap % 5;
        // meshgrid(indexing='xy'): x = g[fh], y = g[fd], z = g[fw]
        float xx = (float)(fh - 2), yy = (float)(fd - 2), zz = (float)(fw - 2);
        float r = sqrtf(xx * xx + yy * yy + zz * zz);
        float rxy = sqrtf(xx * xx + yy * yy);
        float ct = (r > 0.f) ? zz / r : 0.f;
        float st = sqrtf(fmaxf(0.f, 1.f - ct * ct));
        float cp = (rxy > 0.f) ? xx / rxy : 1.f;
        float sp = (rxy > 0.f) ? yy / rxy : 0.f;
        float c2p = cp * cp - sp * sp, s2p = 2.f * cp * sp;
        float c3p = c2p * cp - s2p * sp, s3p = s2p * cp + c2p * sp;

        const float k00 = 0.28209479177387814f;
        const float k10 = 0.48860251190291992f;
        const float c1v = 0.34549414947133547f;
        const float k20 = 0.31539156525252005f;
        const float c21 = 0.77254840404637908f;
        const float c22 = 0.38627420202318954f;
        const float k30 = 0.37317633259011546f;
        const float c31 = 0.32318018411415065f;
        const float c32 = 1.02198547643328236f;
        const float c33 = 0.41722382363278409f;

        float val;
        int deg;
        switch (map) {
            case 0:  deg = 0; val = k00; break;
            case 1:  deg = 1; val = k10 * ct; break;
            case 2:  deg = 1; val = -c1v * st * cp; break;
            case 3:  deg = 1; val = -c1v * st * sp; break;
            case 4:  deg = 2; val = k20 * (3.f * ct * ct - 1.f); break;
            case 5:  deg = 2; val = -c21 * st * ct * cp; break;
            case 6:  deg = 2; val = -c21 * st * ct * sp; break;
            case 7:  deg = 2; val = c22 * st * st * c2p; break;
            case 8:  deg = 2; val = c22 * st * st * s2p; break;
            case 9:  deg = 3; val = k30 * (5.f * ct * ct * ct - 3.f * ct); break;
            case 10: deg = 3; val = -c31 * st * (5.f * ct * ct - 1.f) * cp; break;
            case 11: deg = 3; val = -c31 * st * (5.f * ct * ct - 1.f) * sp; break;
            case 12: deg = 3; val = c32 * st * st * ct * c2p; break;
            case 13: deg = 3; val = c32 * st * st * ct * s2p; break;
            case 14: deg = 3; val = -c33 * st * st * st * c3p; break;
            default: deg = 3; val = -c33 * st * st * st * s3p; break;
        }
        const float scale_tab[16] = {
            1.f,
            0.57735026918962576f, 0.81649658092772603f, 0.81649658092772603f,
            0.44721359549995794f, 0.63245553203367587f, 0.63245553203367587f,
            0.63245553203367587f, 0.63245553203367587f,
            0.37796447300922720f, 0.53452248382484879f, 0.53452248382484879f,
            0.53452248382484879f, 0.53452248382484879f, 0.53452248382484879f,
            0.53452248382484879f};

        float wsum = 0.f;
#pragma unroll
        for (int i = 0; i < 3; ++i) {
            float rad = fmaxf(0.f, 1.f - fabsf(r - (float)i));
            wsum += rad * w[((c * F_ + f) * 3 + i) * 4 + deg];
        }
        outv = wsum * val * scale_tab[map];
    }
    efb[e] = (f16)outv;
}

// ---------------------------------------------------------------------------
// Kernel 2: MFMA main kernel, swapped operands: mfma(filters, voxels, acc)
// -> D[n_row][vox_col]: lane holds maps ksel*4..+3 for voxel vb*16+col.
// A-reads are paired ds_read2_b64 (1 instr = 2 taps x 4ch) via the K-reorder.
// ---------------------------------------------------------------------------
__global__ __launch_bounds__(256, 4) void sshconv_main(
    const float* __restrict__ x, const f16* __restrict__ efb,
    const float* __restrict__ w_cp, const float* __restrict__ b_cp,
    const float* __restrict__ bias, const float* __restrict__ w_proj,
    const float* __restrict__ b_proj, float* __restrict__ out) {
    __shared__ f16 xs[704 * 4];          // padded 8x(8x9+pad) voxels x 4ch (5.5 KB)
    __shared__ int off01[64];            // slot -> (o0 | o1<<16)
    __shared__ f16x2 part2[16 * 64 * 4]; // [f][vox][ksel^f&3] (pa,pb) (16 KB)
    f16* s16 = (f16*)part2;              // overlaid: [vox64][72pad] (9.2 KB)

    const int tid = threadIdx.x;
    const int bt = blockIdx.x;
    const int tw = bt % 12, th = (bt / 12) % 12, td = (bt / 144) % 12, b = bt / 1728;
    const int d0 = td * 4, h0 = th * 4, w0 = tw * 4;

    if (tid < 64) {
        int s = tid, o0, d;
        if (s < 50)      { int fd = s / 10, r = s % 10; o0 = fd * 72 + (r >> 1) * 9 + (r & 1) * 2; d = 1; }
        else if (s < 60) { int q = s - 50; o0 = (q >> 1) * 72 + (q & 1) * 18 + 4; d = 9; }
        else if (s < 63) { int g = s - 60; o0 = g * 144 + 40; d = 72; }
        else             { o0 = 0; d = 0; }
        off01[s] = o0 | ((o0 + d) << 16);
    }
    if (tid < 128) {  // zero tail elems 576..704 (pad-tap reads land here)
        *(f16x4*)&xs[2304 + tid * 4] = (f16x4){(f16)0.f, (f16)0.f, (f16)0.f, (f16)0.f};
    }

    // stage x tile (zero halo), fp32 -> fp16, padded layout d*72+h*9+w
#pragma unroll
    for (int i = 0; i < 2; ++i) {
        int s = tid * 2 + i;  // 0..511
        int sd = s >> 6, sh = (s >> 3) & 7, sw = s & 7;
        int gd = d0 - 2 + sd, gh = h0 - 2 + sh, gw = w0 - 2 + sw;
        float4 v = make_float4(0.f, 0.f, 0.f, 0.f);
        if (gd >= 0 && gd < NVOX && gh >= 0 && gh < NVOX && gw >= 0 && gw < NVOX)
            v = *(const float4*)&x[(((b * NVOX + gd) * NVOX + gh) * NVOX + gw) * 4];
        f16x4 hv = {(f16)v.x, (f16)v.y, (f16)v.z, (f16)v.w};
        *(f16x4*)&xs[(sd * 72 + sh * 9 + sw) * 4] = hv;
    }
    __syncthreads();

    const int lane = tid & 63, wv = tid >> 6;
    const int col = lane & 15, ksel = lane >> 4;
    const int vh = col >> 2, vw = col & 3;
    const int abase = vh * 9 + vw;

    f32x4 acc[4][4];  // [nf][vb]
#pragma unroll
    for (int i = 0; i < 4; ++i)
#pragma unroll
        for (int jj = 0; jj < 4; ++jj) acc[i][jj] = (f32x4){0.f, 0.f, 0.f, 0.f};

    const f16* bptr = efb + ((ksel * 256) + wv * 64 + col) * 8;

#define KSTEP(KB, DELTA, MIXED)                                                \
    {                                                                          \
        const int info = off01[(KB) * 4 + ksel];                               \
        const int o0 = info & 0xFFFF;                                          \
        const int o1 = (MIXED) ? (info >> 16) : (o0 + (DELTA));                \
        f16x8 a[4];                                                            \
        _Pragma("unroll") for (int vb = 0; vb < 4; ++vb) {                     \
            f16x4 lo = *(const f16x4*)&xs[(abase + vb * 72 + o0) * 4];         \
            f16x4 hi = *(const f16x4*)&xs[(abase + vb * 72 + o1) * 4];         \
            a[vb] = __builtin_shufflevector(lo, hi, 0, 1, 2, 3, 4, 5, 6, 7);   \
        }                                                                      \
        f16x8 bf[4];                                                           \
        _Pragma("unroll") for (int nf = 0; nf < 4; ++nf)                       \
            bf[nf] = *(const f16x8*)(bptr + (KB) * 8192 + nf * 128);           \
        _Pragma("unroll") for (int nf = 0; nf < 4; ++nf)                       \
            _Pragma("unroll") for (int vb = 0; vb < 4; ++vb)                   \
                acc[nf][vb] = __builtin_amdgcn_mfma_f32_16x16x32_f16(          \
                    bf[nf], a[vb], acc[nf][vb], 0, 0, 0);                      \
    }

#pragma unroll 2
    for (int kb = 0; kb < 12; ++kb) KSTEP(kb, 1, false)
    KSTEP(12, 0, true)
    KSTEP(13, 9, false)
    KSTEP(14, 9, false)
    KSTEP(15, 72, false)
#undef KSTEP

    // ---- in-register power-spectrum partials -> part2 ----
    float wcp[4][4], bcp[4];
#pragma unroll
    for (int nf = 0; nf < 4; ++nf) {
        const int f = wv * 4 + nf;
        bcp[nf] = b_cp[f];
#pragma unroll
        for (int c = 0; c < 4; ++c) wcp[nf][c] = w_cp[c * F_ + f];
    }

#pragma unroll
    for (int vb = 0; vb < 4; ++vb) {
        f16x4 xc = *(const f16x4*)&xs[((vb + 2) * 72 + (vh + 2) * 9 + (vw + 2)) * 4];
        const float xc0 = (float)xc[0], xc1 = (float)xc[1];
        const float xc2 = (float)xc[2], xc3 = (float)xc[3];
        const int vox = vb * 16 + col;
#pragma unroll
        for (int nf = 0; nf < 4; ++nf) {
            const f32x4 v = acc[nf][vb];
            float cen = bcp[nf] + xc0 * wcp[nf][0] + xc1 * wcp[nf][1] +
                        xc2 * wcp[nf][2] + xc3 * wcp[nf][3];
            float v0 = v[0] + ((ksel == 0) ? cen : 0.f);
            float s0 = v0 * v0, s1 = v[1] * v[1], s2 = v[2] * v[2], s3 = v[3] * v[3];
            float pa = (ksel & 1) ? (s0 + s1) : s0;
            float pb = (ksel & 1) ? (s2 + s3) : (s1 + s2 + s3);
            const int f = wv * 4 + nf;
            part2[(f * 64 + vox) * 4 + (ksel ^ (f & 3))] = (f16x2){(f16)pa, (f16)pb};
        }
    }
    __syncthreads();

    // ---- combine partials + bias + signed-log -> regs ----
    f16 so_all[16];
    {
        const int fc = tid >> 4, vlo = tid & 15;
        const int kx = fc & 3;
        const f32x4 bias4 = *(const f32x4*)&bias[fc * 4];
#pragma unroll
        for (int it = 0; it < 4; ++it) {
            const int vox = it * 16 + vlo;
            const int base = (fc * 64 + vox) * 4;
            f16x2 p0 = part2[base + (0 ^ kx)];
            f16x2 p1 = part2[base + (1 ^ kx)];
            f16x2 p2 = part2[base + (2 ^ kx)];
            f16x2 p3 = part2[base + (3 ^ kx)];
            f32x4 sv = {(float)p0[0], (float)p0[1],
                        (float)p1[0] + (float)p1[1] + (float)p2[0],
                        (float)p2[1] + (float)p3[0] + (float)p3[1]};
#pragma unroll
            for (int n = 0; n < 4; ++n) {
                float vb2 = sv[n] + bias4[n];
                float lg = __builtin_amdgcn_logf(1.f + fabsf(vb2)) * 0.69314718055994531f;
                so_all[it * 4 + n] = (f16)copysignf(lg, vb2);
            }
        }
    }
    __syncthreads();  // all part2 reads done before overlay writes

    // ---- write s16 (overlaid on part2) ----
    {
        const int fc = tid >> 4, vlo = tid & 15;
#pragma unroll
        for (int it = 0; it < 4; ++it) {
            const int vox = it * 16 + vlo;
            *(f16x4*)&s16[vox * 72 + fc * 4] = *(f16x4*)&so_all[it * 4];
        }
    }

    // ---- projection via MFMA: s16[64][64] x w_proj[64][16] ----
    const int fo = lane & 15, kg = lane >> 4;
    f16 wb0[8], wb1[8];
#pragma unroll
    for (int j = 0; j < 8; ++j) {
        wb0[j] = (f16)w_proj[(kg * 8 + j) * F_ + fo];
        wb1[j] = (f16)w_proj[(32 + kg * 8 + j) * F_ + fo];
    }
    const float bpj = b_proj[fo];
    __syncthreads();

    f16x8 a0 = *(const f16x8*)&s16[(wv * 16 + col) * 72 + kg * 8];
    f16x8 a1 = *(const f16x8*)&s16[(wv * 16 + col) * 72 + 32 + kg * 8];
    f32x4 oc = {0.f, 0.f, 0.f, 0.f};
    oc = __builtin_amdgcn_mfma_f32_16x16x32_f16(a0, *(f16x8*)wb0, oc, 0, 0, 0);
    oc = __builtin_amdgcn_mfma_f32_16x16x32_f16(a1, *(f16x8*)wb1, oc, 0, 0, 0);

#pragma unroll
    for (int r = 0; r < 4; ++r) {
        float o = fmaxf(oc[r] + bpj, 0.f);
        out[(((b * NVOX + d0 + wv) * NVOX + h0 + kg) * NVOX + w0 + r) * F_ + fo] = o;
    }
}

extern "C" void kernel_launch(void* const* d_in, const int* in_sizes, int n_in,
                              void* d_out, int out_size, void* d_ws, size_t ws_size,
                              hipStream_t stream) {
    const float* x = (const float*)d_in[0];       // [2,48,48,48,4]
    const float* w = (const float*)d_in[1];       // [4,16,3,4]
    const float* w_cp = (const float*)d_in[2];    // [4,16]
    const float* b_cp = (const float*)d_in[3];    // [16]
    const float* bias = (const float*)d_in[4];    // [64]
    const float* w_proj = (const float*)d_in[5];  // [64,16]
    const float* b_proj = (const float*)d_in[6];  // [16]
    float* out = (float*)d_out;                   // [2,48,48,48,16]
    f16* efb = (f16*)d_ws;                        // 131072 f16 (256 KB)

    build_filters<<<512, 256, 0, stream>>>(w, efb);
    sshconv_main<<<3456, 256, 0, stream>>>(x, efb, w_cp, b_cp, bias, w_proj, b_proj, out);
}

// Round 7
// 64.842 us; speedup vs baseline: 1.1829x; 1.1829x over previous
//
#include <hip/hip_runtime.h>
#include <math.h>

typedef _Float16 f16;
typedef _Float16 f16x2 __attribute__((ext_vector_type(2)));
typedef _Float16 f16x4 __attribute__((ext_vector_type(4)));
typedef _Float16 f16x8 __attribute__((ext_vector_type(8)));
typedef float f32x4 __attribute__((ext_vector_type(4)));

#define NVOX 48
#define F_ 16

// ---------------------------------------------------------------------------
// Kernel 1: build effective filter bank in MFMA fragment layout (round-4 form).
// efb[kq(64)][n(256)][j(8)] f16, K index k = kq*8+j = tap*4 + c, n = f*16+map.
// Taps 125..127 zero-pad. Folds radial shells, degree-shared w, and
// sqrt((m>0?2:1)/(2n+1)) power-spectrum scale.
// ---------------------------------------------------------------------------
__global__ void build_filters(const float* __restrict__ w, f16* __restrict__ efb) {
    int e = blockIdx.x * 256 + threadIdx.x;  // 0..131071
    int j = e & 7;
    int n = (e >> 3) & 255;
    int kq = e >> 11;            // 0..63
    int k = kq * 8 + j;          // 0..511
    int tap = k >> 2, c = k & 3, f = n >> 4, map = n & 15;

    float outv = 0.f;
    if (tap < 125) {
        int fd = tap / 25, fh = (tap / 5) % 5, fw = tap % 5;
        // meshgrid(indexing='xy'): x = g[fh], y = g[fd], z = g[fw]
        float xx = (float)(fh - 2), yy = (float)(fd - 2), zz = (float)(fw - 2);
        float r = sqrtf(xx * xx + yy * yy + zz * zz);
        float rxy = sqrtf(xx * xx + yy * yy);
        float ct = (r > 0.f) ? zz / r : 0.f;
        float st = sqrtf(fmaxf(0.f, 1.f - ct * ct));
        float cp = (rxy > 0.f) ? xx / rxy : 1.f;
        float sp = (rxy > 0.f) ? yy / rxy : 0.f;
        float c2p = cp * cp - sp * sp, s2p = 2.f * cp * sp;
        float c3p = c2p * cp - s2p * sp, s3p = s2p * cp + c2p * sp;

        const float k00 = 0.28209479177387814f;
        const float k10 = 0.48860251190291992f;
        const float c1v = 0.34549414947133547f;
        const float k20 = 0.31539156525252005f;
        const float c21 = 0.77254840404637908f;
        const float c22 = 0.38627420202318954f;
        const float k30 = 0.37317633259011546f;
        const float c31 = 0.32318018411415065f;
        const float c32 = 1.02198547643328236f;
        const float c33 = 0.41722382363278409f;

        float val;
        int deg;
        switch (map) {
            case 0:  deg = 0; val = k00; break;
            case 1:  deg = 1; val = k10 * ct; break;
            case 2:  deg = 1; val = -c1v * st * cp; break;
            case 3:  deg = 1; val = -c1v * st * sp; break;
            case 4:  deg = 2; val = k20 * (3.f * ct * ct - 1.f); break;
            case 5:  deg = 2; val = -c21 * st * ct * cp; break;
            case 6:  deg = 2; val = -c21 * st * ct * sp; break;
            case 7:  deg = 2; val = c22 * st * st * c2p; break;
            case 8:  deg = 2; val = c22 * st * st * s2p; break;
            case 9:  deg = 3; val = k30 * (5.f * ct * ct * ct - 3.f * ct); break;
            case 10: deg = 3; val = -c31 * st * (5.f * ct * ct - 1.f) * cp; break;
            case 11: deg = 3; val = -c31 * st * (5.f * ct * ct - 1.f) * sp; break;
            case 12: deg = 3; val = c32 * st * st * ct * c2p; break;
            case 13: deg = 3; val = c32 * st * st * ct * s2p; break;
            case 14: deg = 3; val = -c33 * st * st * st * c3p; break;
            default: deg = 3; val = -c33 * st * st * st * s3p; break;
        }
        const float scale_tab[16] = {
            1.f,
            0.57735026918962576f, 0.81649658092772603f, 0.81649658092772603f,
            0.44721359549995794f, 0.63245553203367587f, 0.63245553203367587f,
            0.63245553203367587f, 0.63245553203367587f,
            0.37796447300922720f, 0.53452248382484879f, 0.53452248382484879f,
            0.53452248382484879f, 0.53452248382484879f, 0.53452248382484879f,
            0.53452248382484879f};

        float wsum = 0.f;
#pragma unroll
        for (int i = 0; i < 3; ++i) {
            float rad = fmaxf(0.f, 1.f - fabsf(r - (float)i));
            wsum += rad * w[((c * F_ + f) * 3 + i) * 4 + deg];
        }
        outv = wsum * val * scale_tab[map];
    }
    efb[e] = (f16)outv;
}

// ---------------------------------------------------------------------------
// Kernel 2: MFMA main kernel, swapped operands: mfma(filters, voxels, acc).
// Block tile M=128 voxels (4x4x8), staged once as 8x8x12 (stride-12/96),
// processed as two sequential 4x4x4 subtiles using the verified round-4
// K-loop + epilogue. D[n_row][vox_col]: lane holds maps ksel*4..+3 for
// voxel vb*16+col.
// ---------------------------------------------------------------------------
__global__ __launch_bounds__(256, 4) void sshconv_main(
    const float* __restrict__ x, const f16* __restrict__ efb,
    const float* __restrict__ w_cp, const float* __restrict__ b_cp,
    const float* __restrict__ bias, const float* __restrict__ w_proj,
    const float* __restrict__ b_proj, float* __restrict__ out) {
    __shared__ f16 xs[768 * 4];          // 8x8x12 voxels x 4ch fp16 (6 KB)
    __shared__ int off_tab[128];         // tap -> element offset (stride 12/96)
    __shared__ f16x2 part2[16 * 64 * 4]; // [f][vox][ksel^f&3] (pa,pb) (16 KB)
    f16* s16 = (f16*)part2;              // overlaid: [vox64][72pad] (9.2 KB)

    const int tid = threadIdx.x;
    const int bt = blockIdx.x;
    const int tw = bt % 6, th = (bt / 6) % 12, td = (bt / 72) % 12, b = bt / 864;
    const int d0 = td * 4, h0 = th * 4, w0 = tw * 8;

    if (tid < 128) {
        int t = tid;
        off_tab[t] = (t < 125) ? (t / 25) * 96 + ((t / 5) % 5) * 12 + (t % 5) : 0;
    }

    // stage x tile 8x8x12 (zero halo), fp32 -> fp16, elem = sd*96 + sh*12 + sw
#pragma unroll
    for (int i = 0; i < 3; ++i) {
        int s = i * 256 + tid;  // 0..767
        int sd = s / 96, r = s % 96;
        int sh = r / 12, sw = r % 12;
        int gd = d0 - 2 + sd, gh = h0 - 2 + sh, gw = w0 - 2 + sw;
        float4 v = make_float4(0.f, 0.f, 0.f, 0.f);
        if (gd >= 0 && gd < NVOX && gh >= 0 && gh < NVOX && gw >= 0 && gw < NVOX)
            v = *(const float4*)&x[(((b * NVOX + gd) * NVOX + gh) * NVOX + gw) * 4];
        f16x4 hv = {(f16)v.x, (f16)v.y, (f16)v.z, (f16)v.w};
        *(f16x4*)&xs[s * 4] = hv;
    }
    __syncthreads();

    const int lane = tid & 63, wv = tid >> 6;
    const int col = lane & 15, ksel = lane >> 4;
    const int vh = col >> 2, vw = col & 3;
    const f16* bptr = efb + ((ksel * 256) + wv * 64 + col) * 8;

    for (int sub = 0; sub < 2; ++sub) {
        const int abase = vh * 12 + vw + sub * 4;

        f32x4 acc[4][4];  // [nf][vb]
#pragma unroll
        for (int i = 0; i < 4; ++i)
#pragma unroll
            for (int jj = 0; jj < 4; ++jj) acc[i][jj] = (f32x4){0.f, 0.f, 0.f, 0.f};

#pragma unroll 2
        for (int kblk = 0; kblk < 16; ++kblk) {
            const int t0 = kblk * 8 + ksel * 2;
            const int o0 = off_tab[t0], o1 = off_tab[t0 + 1];

            f16x8 a[4];  // voxel fragments (B operand), vb = voxel-d subtile
#pragma unroll
            for (int vb = 0; vb < 4; ++vb) {
                f16x4 lo = *(const f16x4*)&xs[(abase + vb * 96 + o0) * 4];
                f16x4 hi = *(const f16x4*)&xs[(abase + vb * 96 + o1) * 4];
                a[vb] = __builtin_shufflevector(lo, hi, 0, 1, 2, 3, 4, 5, 6, 7);
            }
            f16x8 bf[4];  // filter fragments (A operand), nf = n subtile (f)
#pragma unroll
            for (int nf = 0; nf < 4; ++nf)
                bf[nf] = *(const f16x8*)(bptr + kblk * 8192 + nf * 128);
#pragma unroll
            for (int nf = 0; nf < 4; ++nf)
#pragma unroll
                for (int vb = 0; vb < 4; ++vb)
                    acc[nf][vb] = __builtin_amdgcn_mfma_f32_16x16x32_f16(
                        bf[nf], a[vb], acc[nf][vb], 0, 0, 0);
        }

        // ---- in-register power-spectrum partials -> part2 ----
        float wcp[4][4], bcp[4];
#pragma unroll
        for (int nf = 0; nf < 4; ++nf) {
            const int f = wv * 4 + nf;
            bcp[nf] = b_cp[f];
#pragma unroll
            for (int c = 0; c < 4; ++c) wcp[nf][c] = w_cp[c * F_ + f];
        }

#pragma unroll
        for (int vb = 0; vb < 4; ++vb) {
            f16x4 xc = *(const f16x4*)&xs[((vb + 2) * 96 + (vh + 2) * 12 +
                                           (vw + sub * 4 + 2)) * 4];
            const float xc0 = (float)xc[0], xc1 = (float)xc[1];
            const float xc2 = (float)xc[2], xc3 = (float)xc[3];
            const int vox = vb * 16 + col;
#pragma unroll
            for (int nf = 0; nf < 4; ++nf) {
                const f32x4 v = acc[nf][vb];
                float cen = bcp[nf] + xc0 * wcp[nf][0] + xc1 * wcp[nf][1] +
                            xc2 * wcp[nf][2] + xc3 * wcp[nf][3];
                float v0 = v[0] + ((ksel == 0) ? cen : 0.f);
                float s0 = v0 * v0, s1 = v[1] * v[1], s2 = v[2] * v[2], s3 = v[3] * v[3];
                float pa = (ksel & 1) ? (s0 + s1) : s0;
                float pb = (ksel & 1) ? (s2 + s3) : (s1 + s2 + s3);
                const int f = wv * 4 + nf;
                part2[(f * 64 + vox) * 4 + (ksel ^ (f & 3))] = (f16x2){(f16)pa, (f16)pb};
            }
        }
        __syncthreads();

        // ---- combine partials + bias + signed-log -> regs ----
        f16 so_all[16];
        {
            const int fc = tid >> 4, vlo = tid & 15;
            const int kx = fc & 3;
            const f32x4 bias4 = *(const f32x4*)&bias[fc * 4];
#pragma unroll
            for (int it = 0; it < 4; ++it) {
                const int vox = it * 16 + vlo;
                const int base = (fc * 64 + vox) * 4;
                f16x2 p0 = part2[base + (0 ^ kx)];
                f16x2 p1 = part2[base + (1 ^ kx)];
                f16x2 p2 = part2[base + (2 ^ kx)];
                f16x2 p3 = part2[base + (3 ^ kx)];
                f32x4 sv = {(float)p0[0], (float)p0[1],
                            (float)p1[0] + (float)p1[1] + (float)p2[0],
                            (float)p2[1] + (float)p3[0] + (float)p3[1]};
#pragma unroll
                for (int n = 0; n < 4; ++n) {
                    float vb2 = sv[n] + bias4[n];
                    float lg = __builtin_amdgcn_logf(1.f + fabsf(vb2)) * 0.69314718055994531f;
                    so_all[it * 4 + n] = (f16)copysignf(lg, vb2);
                }
            }
        }
        __syncthreads();  // all part2 reads done before overlay writes

        // ---- write s16 (overlaid on part2) ----
        {
            const int fc = tid >> 4, vlo = tid & 15;
#pragma unroll
            for (int it = 0; it < 4; ++it) {
                const int vox = it * 16 + vlo;
                *(f16x4*)&s16[vox * 72 + fc * 4] = *(f16x4*)&so_all[it * 4];
            }
        }

        // ---- projection via MFMA: s16[64][64] x w_proj[64][16] ----
        const int fo = lane & 15, kg = lane >> 4;
        f16 wb0[8], wb1[8];
#pragma unroll
        for (int j = 0; j < 8; ++j) {
            wb0[j] = (f16)w_proj[(kg * 8 + j) * F_ + fo];
            wb1[j] = (f16)w_proj[(32 + kg * 8 + j) * F_ + fo];
        }
        const float bpj = b_proj[fo];
        __syncthreads();

        f16x8 a0 = *(const f16x8*)&s16[(wv * 16 + col) * 72 + kg * 8];
        f16x8 a1 = *(const f16x8*)&s16[(wv * 16 + col) * 72 + 32 + kg * 8];
        f32x4 oc = {0.f, 0.f, 0.f, 0.f};
        oc = __builtin_amdgcn_mfma_f32_16x16x32_f16(a0, *(f16x8*)wb0, oc, 0, 0, 0);
        oc = __builtin_amdgcn_mfma_f32_16x16x32_f16(a1, *(f16x8*)wb1, oc, 0, 0, 0);

#pragma unroll
        for (int r = 0; r < 4; ++r) {
            float o = fmaxf(oc[r] + bpj, 0.f);
            out[(((b * NVOX + d0 + wv) * NVOX + h0 + kg) * NVOX + w0 + sub * 4 + r) * F_ + fo] = o;
        }
        __syncthreads();  // protect s16/part2 overlay before next subtile writes
    }
}

extern "C" void kernel_launch(void* const* d_in, const int* in_sizes, int n_in,
                              void* d_out, int out_size, void* d_ws, size_t ws_size,
                              hipStream_t stream) {
    const float* x = (const float*)d_in[0];       // [2,48,48,48,4]
    const float* w = (const float*)d_in[1];       // [4,16,3,4]
    const float* w_cp = (const float*)d_in[2];    // [4,16]
    const float* b_cp = (const float*)d_in[3];    // [16]
    const float* bias = (const float*)d_in[4];    // [64]
    const float* w_proj = (const float*)d_in[5];  // [64,16]
    const float* b_proj = (const float*)d_in[6];  // [16]
    float* out = (float*)d_out;                   // [2,48,48,48,16]
    f16* efb = (f16*)d_ws;                        // 131072 f16 (256 KB)

    build_filters<<<512, 256, 0, stream>>>(w, efb);
    sshconv_main<<<1728, 256, 0, stream>>>(x, efb, w_cp, b_cp, bias, w_proj, b_proj, out);
}